// Round 14
// baseline (760.301 us; speedup 1.0000x reference)
//
#include <hip/hip_runtime.h>
#include <hip/hip_fp16.h>
#include <hip/hip_cooperative_groups.h>
#include <math.h>

namespace cg = cooperative_groups;

#define N_NODES 50000
#define N_EDGES 800000
#define N_GRAPHS 1024
#define DIM 64
#define PAD 64           // padded CSR slots per destination (max in-degree ~45)
#define ZROW N_NODES     // index of the guaranteed-zero row in t'
#define SLICE 6250       // N_NODES / 8 destinations per XCD slice
#define QBLK 208         // deg_fill blocks per slice

// ---------------- one-pass padded-CSR build, XCD-sliced ----------------

__global__ void deg_fill(const int* __restrict__ row, const int* __restrict__ col,
                         int* __restrict__ ideg, int* __restrict__ esrc_pad) {
    int slice = blockIdx.x & 7;
    int q = blockIdx.x >> 3;          // 0..QBLK-1
    int lo = slice * SLICE, hi = lo + SLICE;
    for (int e = q * 256 + threadIdx.x; e < N_EDGES; e += QBLK * 256) {
        int c = col[e];
        if (c >= lo && c < hi) {
            int rank = atomicAdd(&ideg[c], 1);
            if (rank < PAD) esrc_pad[c * PAD + rank] = row[e];
        }
    }
}

// ---------------- shared-memory union for the mega kernel ----------------

struct SharedMem {
    union {
        struct { float At[64][68]; float Bl[64][68]; } g;   // gemm64: 34816 B
        float W9[9 * DIM];                                  // gemm9 staging
        struct { float smax[4][DIM]; float ssum[4][DIM]; int bounds[2]; } p;  // pool
    };
};

// ---------------- helpers ----------------

__device__ __forceinline__ float4 h4tof4(uint2 v) {
    __half2 a = *reinterpret_cast<const __half2*>(&v.x);
    __half2 c = *reinterpret_cast<const __half2*>(&v.y);
    float2 fa = __half22float2(a);
    float2 fc = __half22float2(c);
    return make_float4(fa.x, fa.y, fc.x, fc.y);
}

__device__ __forceinline__ void add4(float4& a, const float4& r) {
    a.x += r.x; a.y += r.y; a.z += r.z; a.w += r.w;
}

__device__ __forceinline__ int lower_bound(const int* a, int n, int key) {
    int lo = 0, hi = n;
    while (lo < hi) {
        int mid = (lo + hi) >> 1;
        if (a[mid] < key) lo = mid + 1; else hi = mid;
    }
    return lo;
}

// ---------------- phase bodies ----------------

// gather + bias + tanh: group-per-node, 16-deep, 64 gathers in flight/wave
__device__ void gather_phase(const int* __restrict__ esrc_pad, const int* __restrict__ ideg,
                             const uint2* __restrict__ th2, const float* __restrict__ b,
                             float4* __restrict__ hout4) {
    int tid = threadIdx.x;
    int wid = tid >> 6;
    int lane = tid & 63;
    int sub = lane & 15;
    int grp = lane >> 4;
    for (int t = blockIdx.x; t < N_NODES / 16; t += gridDim.x) {
        int node = t * 16 + wid * 4 + grp;
        int deg = min(ideg[node], PAD);
        const int* ep = esrc_pad + node * PAD;

        float4 acc0 = h4tof4(th2[(size_t)node * 16 + sub]);  // self-loop
        float4 acc1 = make_float4(0.f, 0.f, 0.f, 0.f);
        float4 acc2 = make_float4(0.f, 0.f, 0.f, 0.f);
        float4 acc3 = make_float4(0.f, 0.f, 0.f, 0.f);

        for (int base = 0; base < deg; base += 16) {
            int4 i0 = *(const int4*)(ep + base + 0);
            int4 i1 = *(const int4*)(ep + base + 4);
            int4 i2 = *(const int4*)(ep + base + 8);
            int4 i3 = *(const int4*)(ep + base + 12);
            int idx[16] = {i0.x, i0.y, i0.z, i0.w, i1.x, i1.y, i1.z, i1.w,
                           i2.x, i2.y, i2.z, i2.w, i3.x, i3.y, i3.z, i3.w};
            int rem = deg - base;  // clamp tail (poisoned ws!) before address calc
            uint2 r[16];
#pragma unroll
            for (int j = 0; j < 16; ++j) {
                int s = (j < rem) ? idx[j] : ZROW;
                r[j] = th2[(size_t)s * 16 + sub];
            }
#pragma unroll
            for (int j = 0; j < 16; ++j) {
                float4 v = h4tof4(r[j]);
                if ((j & 3) == 0) add4(acc0, v);
                else if ((j & 3) == 1) add4(acc1, v);
                else if ((j & 3) == 2) add4(acc2, v);
                else add4(acc3, v);
            }
        }

        float4 acc;
        acc.x = (acc0.x + acc1.x) + (acc2.x + acc3.x);
        acc.y = (acc0.y + acc1.y) + (acc2.y + acc3.y);
        acc.z = (acc0.z + acc1.z) + (acc2.z + acc3.z);
        acc.w = (acc0.w + acc1.w) + (acc2.w + acc3.w);

        float4 bv = ((const float4*)b)[sub];
        float dv = rsqrtf((float)deg + 1.0f);
        float4 res;
        res.x = tanhf(dv * acc.x + bv.x);
        res.y = tanhf(dv * acc.y + bv.y);
        res.z = tanhf(dv * acc.z + bv.z);
        res.w = tanhf(dv * acc.w + bv.w);
        hout4[(size_t)node * 16 + sub] = res;
    }
}

// 64x64 register-tile GEMM; W staged in LDS once per layer, A per tile.
__device__ void gemm64_phase(SharedMem* sh, const float* __restrict__ h,
                             const float* __restrict__ W, const int* __restrict__ ideg,
                             uint2* __restrict__ th2) {
    int tid = threadIdx.x;
    {
        const float4* W4 = (const float4*)W;
#pragma unroll
        for (int i = 0; i < 4; ++i) {
            int idx = tid + 256 * i;
            int k = idx >> 4;
            int d4 = idx & 15;
            *(float4*)&sh->g.Bl[k][d4 * 4] = W4[idx];
        }
    }
    __syncthreads();
    int ty = tid >> 4;
    int tx = tid & 15;
    for (int t = blockIdx.x; t < (N_NODES + 63) / 64; t += gridDim.x) {
        int n0 = t * 64;
        {
            int node = tid >> 2;
            int seg = tid & 3;
            int gn = n0 + node;
            bool ok = gn < N_NODES;
            const float4* h4 = (const float4*)h;
#pragma unroll
            for (int i = 0; i < 4; ++i) {
                int c4 = seg * 4 + i;
                float4 v = ok ? h4[(size_t)gn * 16 + c4] : make_float4(0.f, 0.f, 0.f, 0.f);
                int d = c4 * 4;
                sh->g.At[d + 0][node] = v.x;
                sh->g.At[d + 1][node] = v.y;
                sh->g.At[d + 2][node] = v.z;
                sh->g.At[d + 3][node] = v.w;
            }
        }
        __syncthreads();

        float c00 = 0, c01 = 0, c02 = 0, c03 = 0;
        float c10 = 0, c11 = 0, c12 = 0, c13 = 0;
        float c20 = 0, c21 = 0, c22 = 0, c23 = 0;
        float c30 = 0, c31 = 0, c32 = 0, c33 = 0;
#pragma unroll 8
        for (int k = 0; k < 64; ++k) {
            float4 a = *(const float4*)&sh->g.At[k][ty * 4];
            float4 b = *(const float4*)&sh->g.Bl[k][tx * 4];
            c00 += a.x * b.x; c01 += a.x * b.y; c02 += a.x * b.z; c03 += a.x * b.w;
            c10 += a.y * b.x; c11 += a.y * b.y; c12 += a.y * b.z; c13 += a.y * b.w;
            c20 += a.z * b.x; c21 += a.z * b.y; c22 += a.z * b.z; c23 += a.z * b.w;
            c30 += a.w * b.x; c31 += a.w * b.y; c32 += a.w * b.z; c33 += a.w * b.w;
        }
        int gn = n0 + ty * 4;
#define STORE_ROW(r, CA, CB, CC, CD)                                          \
        if (gn + r < N_NODES) {                                               \
            float dv = rsqrtf((float)ideg[gn + r] + 1.0f);                    \
            __half2 p0 = __floats2half2_rn(dv * CA, dv * CB);                 \
            __half2 p1 = __floats2half2_rn(dv * CC, dv * CD);                 \
            uint2 o;                                                          \
            o.x = *(unsigned*)&p0;                                            \
            o.y = *(unsigned*)&p1;                                            \
            th2[(size_t)(gn + r) * 16 + tx] = o;                              \
        }
        STORE_ROW(0, c00, c01, c02, c03)
        STORE_ROW(1, c10, c11, c12, c13)
        STORE_ROW(2, c20, c21, c22, c23)
        STORE_ROW(3, c30, c31, c32, c33)
#undef STORE_ROW
        __syncthreads();  // At reused next iteration
    }
}

// ---------------- the cooperative mega kernel ----------------

__global__ __launch_bounds__(256, 2) void mega(
    const float* __restrict__ x,
    const float* __restrict__ W0, const float* __restrict__ b0,
    const float* __restrict__ W1, const float* __restrict__ b1,
    const float* __restrict__ W2, const float* __restrict__ b2,
    const float* __restrict__ W3, const float* __restrict__ b3,
    const float* __restrict__ Wout, const float* __restrict__ bout,
    const int* __restrict__ batch,
    const int* __restrict__ ideg, const int* __restrict__ esrc_pad,
    __half* __restrict__ th, float* __restrict__ hA,
    float* __restrict__ out)
{
    cg::grid_group grid = cg::this_grid();
    __shared__ SharedMem sh;
    int tid = threadIdx.x;

    // ---- gemm9: t' = dinv * (x @ W0), fp16 ----
    for (int i = tid; i < 9 * DIM; i += 256) sh.W9[i] = W0[i];
    __syncthreads();
    for (int t = blockIdx.x; t < N_NODES / 4; t += gridDim.x) {
        int node = t * 4 + (tid >> 6);
        int d = tid & 63;
        const float* xr = x + (size_t)node * 9;
        float acc = 0.f;
#pragma unroll
        for (int k = 0; k < 9; ++k) acc += xr[k] * sh.W9[k * DIM + d];
        float dv = rsqrtf((float)ideg[node] + 1.0f);
        th[(size_t)node * DIM + d] = __float2half(dv * acc);
    }
    grid.sync();

    // ---- layer 0 gather ----
    gather_phase(esrc_pad, ideg, (const uint2*)th, b0, (float4*)hA);
    grid.sync();

    // ---- layers 1-3 ----
    const float* Ws[3] = {W1, W2, W3};
    const float* bs[3] = {b1, b2, b3};
    for (int l = 0; l < 3; ++l) {
        gemm64_phase(&sh, hA, Ws[l], ideg, (uint2*)th);
        grid.sync();
        gather_phase(esrc_pad, ideg, (const uint2*)th, bs[l], (float4*)hA);
        grid.sync();
    }

    // ---- pooling + output ----
    for (int g = blockIdx.x; g < N_GRAPHS; g += gridDim.x) {
        int w = tid >> 6, d = tid & 63;
        if (tid == 0) {
            sh.p.bounds[0] = lower_bound(batch, N_NODES, g);
            sh.p.bounds[1] = lower_bound(batch, N_NODES, g + 1);
        }
        __syncthreads();
        int start = sh.p.bounds[0], end = sh.p.bounds[1];
        float mx = -INFINITY, sum = 0.0f;
        for (int n = start + w; n < end; n += 4) {
            float v = hA[(size_t)n * DIM + d];
            mx = fmaxf(mx, v);
            sum += v;
        }
        sh.p.smax[w][d] = mx;
        sh.p.ssum[w][d] = sum;
        __syncthreads();
        if (w == 0) {
            mx = fmaxf(fmaxf(sh.p.smax[0][d], sh.p.smax[1][d]),
                       fmaxf(sh.p.smax[2][d], sh.p.smax[3][d]));
            sum = sh.p.ssum[0][d] + sh.p.ssum[1][d] + sh.p.ssum[2][d] + sh.p.ssum[3][d];
            float cnt = (float)(end - start);
            float mean = sum / fmaxf(cnt, 1.0f);
            float v = mx * Wout[d] + mean * Wout[DIM + d];
#pragma unroll
            for (int off2 = 32; off2 > 0; off2 >>= 1) v += __shfl_down(v, off2, 64);
            if (d == 0) out[g] = v + bout[0];
        }
        __syncthreads();  // shared reused next graph
    }
}

// ---------------- launch ----------------

static inline size_t align256(size_t x) { return (x + 255) & ~(size_t)255; }

extern "C" void kernel_launch(void* const* d_in, const int* in_sizes, int n_in,
                              void* d_out, int out_size, void* d_ws, size_t ws_size,
                              hipStream_t stream) {
    const float* x     = (const float*)d_in[0];
    const int*   ei    = (const int*)d_in[1];
    const int*   batch = (const int*)d_in[2];
    const float* W0    = (const float*)d_in[3];
    const float* b0    = (const float*)d_in[4];
    const float* W1    = (const float*)d_in[5];
    const float* b1    = (const float*)d_in[6];
    const float* W2    = (const float*)d_in[7];
    const float* b2    = (const float*)d_in[8];
    const float* W3    = (const float*)d_in[9];
    const float* b3    = (const float*)d_in[10];
    const float* Wout  = (const float*)d_in[11];
    const float* bout  = (const float*)d_in[12];
    float* out = (float*)d_out;

    const int* row = ei;            // source
    const int* col = ei + N_EDGES;  // destination

    char* ws = (char*)d_ws;
    size_t off = 0;
    int*    ideg     = (int*)(ws + off);    off += align256((size_t)N_NODES * 4);
    int*    esrc_pad = (int*)(ws + off);    off += align256((size_t)N_NODES * PAD * 4);
    __half* th       = (__half*)(ws + off); off += align256(((size_t)N_NODES + 1) * DIM * 2);
    float*  hA       = (float*)(ws + off);  off += align256((size_t)N_NODES * DIM * 4);
    (void)ws_size;

    // padded-CSR build (XCD-sliced) + zero inits
    hipMemsetAsync(ideg, 0, (size_t)N_NODES * 4, stream);
    hipMemsetAsync(th + (size_t)ZROW * DIM, 0, DIM * 2, stream);
    deg_fill<<<8 * QBLK, 256, 0, stream>>>(row, col, ideg, esrc_pad);

    // size the cooperative grid from the runtime's own occupancy calc
    // (deterministic host-side query; R13's fixed 768 exceeded the coop limit
    //  and the launch silently failed)
    static int blocks_per_cu = -1;
    if (blocks_per_cu < 0) {
        int occ = 0;
        hipOccupancyMaxActiveBlocksPerMultiprocessor(&occ, (const void*)mega, 256, 0);
        blocks_per_cu = occ < 1 ? 1 : (occ > 2 ? 2 : occ);
    }
    int mblocks = blocks_per_cu * 256;

    void* args[] = {(void*)&x,
                    (void*)&W0, (void*)&b0, (void*)&W1, (void*)&b1,
                    (void*)&W2, (void*)&b2, (void*)&W3, (void*)&b3,
                    (void*)&Wout, (void*)&bout, (void*)&batch,
                    (void*)&ideg, (void*)&esrc_pad, (void*)&th, (void*)&hA,
                    (void*)&out};
    hipLaunchCooperativeKernel((void*)mega, dim3(mblocks), dim3(256), args, 0, stream);
    (void)out_size; (void)n_in; (void)in_sizes;
}

// Round 15
// 274.546 us; speedup vs baseline: 2.7693x; 2.7693x over previous
//
#include <hip/hip_runtime.h>
#include <hip/hip_fp16.h>
#include <math.h>

#define N_NODES 50000
#define N_EDGES 800000
#define N_GRAPHS 1024
#define DIM 64
#define PAD 64           // padded CSR slots per destination (max in-degree ~45)
#define ZROW N_NODES     // index of the guaranteed-zero row in t'
#define SLICE 6250       // N_NODES / 8 destinations per XCD slice
#define QBLK 208         // blocks per slice

// ---------------- one-pass padded-CSR build, XCD-sliced ----------------
// slice s = blockIdx & 7 owns dests [s*SLICE, (s+1)*SLICE). Blocks of one
// slice land on one XCD (dispatch round-robin), so esrc_pad writes for a
// slice coalesce in that XCD's L2 instead of 8 partial dirty copies.

__global__ void deg_fill(const int* __restrict__ row, const int* __restrict__ col,
                         int* __restrict__ ideg, int* __restrict__ esrc_pad) {
    int slice = blockIdx.x & 7;
    int q = blockIdx.x >> 3;          // 0..QBLK-1
    int lo = slice * SLICE, hi = lo + SLICE;
    for (int e = q * 256 + threadIdx.x; e < N_EDGES; e += QBLK * 256) {
        int c = col[e];
        if (c >= lo && c < hi) {
            int rank = atomicAdd(&ideg[c], 1);
            if (rank < PAD) esrc_pad[c * PAD + rank] = row[e];
        }
    }
}

// ---------------- dense transforms (t' = dinv * (h @ W), fp16) ----------------

__global__ void gemm9(const float* __restrict__ x, const float* __restrict__ W,
                      const int* __restrict__ ideg, __half* __restrict__ th) {
    __shared__ float Wl[9 * DIM];
    int tid = threadIdx.x;
    for (int i = tid; i < 9 * DIM; i += 256) Wl[i] = W[i];
    __syncthreads();
    int node = blockIdx.x * 4 + (tid >> 6);
    int d = tid & 63;
    if (node >= N_NODES) return;
    const float* xr = x + (size_t)node * 9;
    float acc = 0.0f;
#pragma unroll
    for (int k = 0; k < 9; ++k) acc += xr[k] * Wl[k * DIM + d];
    float dv = rsqrtf((float)ideg[node] + 1.0f);
    th[(size_t)node * DIM + d] = __float2half(dv * acc);
}

// layers 1-3: 64x64 register-tile GEMM, 64-node tiles, fp16+dinv output.
__global__ void gemm64(const float* __restrict__ h, const float* __restrict__ W,
                       const int* __restrict__ ideg, uint2* __restrict__ th2) {
    __shared__ float At[64][68];
    __shared__ float Bl[64][68];
    int tid = threadIdx.x;
    int n0 = blockIdx.x * 64;

    {
        const float4* W4 = (const float4*)W;
#pragma unroll
        for (int i = 0; i < 4; ++i) {
            int idx = tid + 256 * i;
            int k = idx >> 4;
            int d4 = idx & 15;
            float4 v = W4[idx];
            *(float4*)&Bl[k][d4 * 4] = v;
        }
    }
    {
        int node = tid >> 2;
        int seg = tid & 3;
        int gn = n0 + node;
        bool ok = gn < N_NODES;
        const float4* h4 = (const float4*)h;
#pragma unroll
        for (int i = 0; i < 4; ++i) {
            int c4 = seg * 4 + i;
            float4 v = ok ? h4[(size_t)gn * 16 + c4] : make_float4(0.f, 0.f, 0.f, 0.f);
            int d = c4 * 4;
            At[d + 0][node] = v.x;
            At[d + 1][node] = v.y;
            At[d + 2][node] = v.z;
            At[d + 3][node] = v.w;
        }
    }
    __syncthreads();

    int ty = tid >> 4;
    int tx = tid & 15;
    float c00 = 0, c01 = 0, c02 = 0, c03 = 0;
    float c10 = 0, c11 = 0, c12 = 0, c13 = 0;
    float c20 = 0, c21 = 0, c22 = 0, c23 = 0;
    float c30 = 0, c31 = 0, c32 = 0, c33 = 0;
#pragma unroll 8
    for (int k = 0; k < 64; ++k) {
        float4 a = *(const float4*)&At[k][ty * 4];
        float4 b = *(const float4*)&Bl[k][tx * 4];
        c00 += a.x * b.x; c01 += a.x * b.y; c02 += a.x * b.z; c03 += a.x * b.w;
        c10 += a.y * b.x; c11 += a.y * b.y; c12 += a.y * b.z; c13 += a.y * b.w;
        c20 += a.z * b.x; c21 += a.z * b.y; c22 += a.z * b.z; c23 += a.z * b.w;
        c30 += a.w * b.x; c31 += a.w * b.y; c32 += a.w * b.z; c33 += a.w * b.w;
    }
    int gn = n0 + ty * 4;
#define STORE_ROW(r, CA, CB, CC, CD)                                          \
    if (gn + r < N_NODES) {                                                   \
        float dv = rsqrtf((float)ideg[gn + r] + 1.0f);                        \
        __half2 p0 = __floats2half2_rn(dv * CA, dv * CB);                     \
        __half2 p1 = __floats2half2_rn(dv * CC, dv * CD);                     \
        uint2 o;                                                              \
        o.x = *(unsigned*)&p0;                                                \
        o.y = *(unsigned*)&p1;                                                \
        th2[(size_t)(gn + r) * 16 + tx] = o;                                  \
    }
    STORE_ROW(0, c00, c01, c02, c03)
    STORE_ROW(1, c10, c11, c12, c13)
    STORE_ROW(2, c20, c21, c22, c23)
    STORE_ROW(3, c30, c31, c32, c33)
#undef STORE_ROW
}

// ---------------- gather + bias + tanh: group-per-node, 16-deep ----------------
// wave = 4 groups x 16 lanes; group g owns node base+g and issues its 16
// edge-slots in one batch -> 64 row-gathers in flight per wave, zero shuffles.
// out[n] = tanh( dinv[n] * (t'[n] + sum_e t'[src_e]) + b )

__device__ __forceinline__ float4 h4tof4(uint2 v) {
    __half2 a = *reinterpret_cast<const __half2*>(&v.x);
    __half2 c = *reinterpret_cast<const __half2*>(&v.y);
    float2 fa = __half22float2(a);
    float2 fc = __half22float2(c);
    return make_float4(fa.x, fa.y, fc.x, fc.y);
}

__device__ __forceinline__ void add4(float4& a, const float4& r) {
    a.x += r.x; a.y += r.y; a.z += r.z; a.w += r.w;
}

__global__ void gather_tanh(const int* __restrict__ esrc_pad, const int* __restrict__ ideg,
                            const uint2* __restrict__ th2, const float* __restrict__ b,
                            float4* __restrict__ hout4) {
    int tid = threadIdx.x;
    int wid = tid >> 6;
    int lane = tid & 63;
    int sub = lane & 15;   // half4 chunk: dims [4*sub, 4*sub+4)
    int grp = lane >> 4;   // 0..3 -> node
    int node = blockIdx.x * 16 + wid * 4 + grp;  // grid = N_NODES/16 = 3125

    int deg = min(ideg[node], PAD);
    const int* ep = esrc_pad + node * PAD;

    // self-loop + 4 split accumulators for FMA ILP
    float4 acc0 = h4tof4(th2[(size_t)node * 16 + sub]);
    float4 acc1 = make_float4(0.f, 0.f, 0.f, 0.f);
    float4 acc2 = make_float4(0.f, 0.f, 0.f, 0.f);
    float4 acc3 = make_float4(0.f, 0.f, 0.f, 0.f);

    for (int base = 0; base < deg; base += 16) {
        int4 i0 = *(const int4*)(ep + base + 0);
        int4 i1 = *(const int4*)(ep + base + 4);
        int4 i2 = *(const int4*)(ep + base + 8);
        int4 i3 = *(const int4*)(ep + base + 12);
        int idx[16] = {i0.x, i0.y, i0.z, i0.w, i1.x, i1.y, i1.z, i1.w,
                       i2.x, i2.y, i2.z, i2.w, i3.x, i3.y, i3.z, i3.w};
        // clamp tail slots (poisoned ws!) to the zero row BEFORE address calc
        int rem = deg - base;
        uint2 r[16];
#pragma unroll
        for (int j = 0; j < 16; ++j) {
            int s = (j < rem) ? idx[j] : ZROW;
            r[j] = th2[(size_t)s * 16 + sub];
        }
#pragma unroll
        for (int j = 0; j < 16; ++j) {
            float4 v = h4tof4(r[j]);
            if ((j & 3) == 0) add4(acc0, v);
            else if ((j & 3) == 1) add4(acc1, v);
            else if ((j & 3) == 2) add4(acc2, v);
            else add4(acc3, v);
        }
    }

    float4 acc;
    acc.x = (acc0.x + acc1.x) + (acc2.x + acc3.x);
    acc.y = (acc0.y + acc1.y) + (acc2.y + acc3.y);
    acc.z = (acc0.z + acc1.z) + (acc2.z + acc3.z);
    acc.w = (acc0.w + acc1.w) + (acc2.w + acc3.w);

    float4 bv = ((const float4*)b)[sub];
    float dv = rsqrtf((float)deg + 1.0f);
    float4 res;
    res.x = tanhf(dv * acc.x + bv.x);
    res.y = tanhf(dv * acc.y + bv.y);
    res.z = tanhf(dv * acc.z + bv.z);
    res.w = tanhf(dv * acc.w + bv.w);
    hout4[(size_t)node * 16 + sub] = res;
}

// ---------------- pooling + output ----------------

__device__ __forceinline__ int lower_bound(const int* a, int n, int key) {
    int lo = 0, hi = n;
    while (lo < hi) {
        int mid = (lo + hi) >> 1;
        if (a[mid] < key) lo = mid + 1; else hi = mid;
    }
    return lo;
}

__global__ void pool_out(const float* __restrict__ h, const int* __restrict__ batch,
                         const float* __restrict__ Wout, const float* __restrict__ bout,
                         float* __restrict__ out) {
    __shared__ float smax[4][DIM];
    __shared__ float ssum[4][DIM];
    __shared__ int bounds[2];
    int g = blockIdx.x;
    int tid = threadIdx.x, w = tid >> 6, d = tid & 63;
    if (tid == 0) {
        bounds[0] = lower_bound(batch, N_NODES, g);
        bounds[1] = lower_bound(batch, N_NODES, g + 1);
    }
    __syncthreads();
    int start = bounds[0], end = bounds[1];
    float mx = -INFINITY, sum = 0.0f;
    for (int n = start + w; n < end; n += 4) {
        float v = h[(size_t)n * DIM + d];
        mx = fmaxf(mx, v);
        sum += v;
    }
    smax[w][d] = mx;
    ssum[w][d] = sum;
    __syncthreads();
    if (w == 0) {
        mx = fmaxf(fmaxf(smax[0][d], smax[1][d]), fmaxf(smax[2][d], smax[3][d]));
        sum = ssum[0][d] + ssum[1][d] + ssum[2][d] + ssum[3][d];
        float cnt = (float)(end - start);
        float mean = sum / fmaxf(cnt, 1.0f);
        float v = mx * Wout[d] + mean * Wout[DIM + d];
#pragma unroll
        for (int off = 32; off > 0; off >>= 1) v += __shfl_down(v, off, 64);
        if (d == 0) out[g] = v + bout[0];
    }
}

// ---------------- launch ----------------

static inline size_t align256(size_t x) { return (x + 255) & ~(size_t)255; }

extern "C" void kernel_launch(void* const* d_in, const int* in_sizes, int n_in,
                              void* d_out, int out_size, void* d_ws, size_t ws_size,
                              hipStream_t stream) {
    const float* x     = (const float*)d_in[0];
    const int*   ei    = (const int*)d_in[1];
    const int*   batch = (const int*)d_in[2];
    const float* W0    = (const float*)d_in[3];
    const float* b0    = (const float*)d_in[4];
    const float* W1    = (const float*)d_in[5];
    const float* b1    = (const float*)d_in[6];
    const float* W2    = (const float*)d_in[7];
    const float* b2    = (const float*)d_in[8];
    const float* W3    = (const float*)d_in[9];
    const float* b3    = (const float*)d_in[10];
    const float* Wout  = (const float*)d_in[11];
    const float* bout  = (const float*)d_in[12];
    float* out = (float*)d_out;

    const int* row = ei;            // source
    const int* col = ei + N_EDGES;  // destination

    char* ws = (char*)d_ws;
    size_t off = 0;
    int*    ideg     = (int*)(ws + off);    off += align256((size_t)N_NODES * 4);
    int*    esrc_pad = (int*)(ws + off);    off += align256((size_t)N_NODES * PAD * 4);
    __half* th       = (__half*)(ws + off); off += align256(((size_t)N_NODES + 1) * DIM * 2);
    float*  hA       = (float*)(ws + off);  off += align256((size_t)N_NODES * DIM * 4);
    (void)ws_size;

    const int wave_blocks = N_NODES / 4;             // 12500 (gemm9)
    const int gath_blocks = N_NODES / 16;            // 3125  (4 nodes/wave)
    const int gemm_blocks = (N_NODES + 63) / 64;     // 782

    // one-pass padded-CSR build (XCD-sliced) + zero-row init
    hipMemsetAsync(ideg, 0, (size_t)N_NODES * 4, stream);
    hipMemsetAsync(th + (size_t)ZROW * DIM, 0, DIM * 2, stream);
    deg_fill<<<8 * QBLK, 256, 0, stream>>>(row, col, ideg, esrc_pad);

    // layer 0
    gemm9<<<wave_blocks, 256, 0, stream>>>(x, W0, ideg, th);
    gather_tanh<<<gath_blocks, 256, 0, stream>>>(esrc_pad, ideg, (const uint2*)th, b0, (float4*)hA);

    // layers 1-3
    const float* Ws[3] = {W1, W2, W3};
    const float* bs[3] = {b1, b2, b3};
    for (int l = 0; l < 3; ++l) {
        gemm64<<<gemm_blocks, 256, 0, stream>>>(hA, Ws[l], ideg, (uint2*)th);
        gather_tanh<<<gath_blocks, 256, 0, stream>>>(esrc_pad, ideg, (const uint2*)th, bs[l], (float4*)hA);
    }

    // pooling + output
    pool_out<<<N_GRAPHS, 256, 0, stream>>>(hA, batch, Wout, bout, out);
    (void)out_size; (void)n_in; (void)in_sizes;
}